// Round 2
// baseline (6339.015 us; speedup 1.0000x reference)
//
#include <hip/hip_runtime.h>
#include <hip/hip_bf16.h>
#include <math.h>

#define H_HEADS 8
constexpr float LN_EPS = 1e-5f;

// ---------- float atomic-max via order-preserving uint encoding ----------
__device__ __forceinline__ unsigned enc_f(float f){
  unsigned u = __float_as_uint(f);
  return (u & 0x80000000u) ? ~u : (u | 0x80000000u);
}
__device__ __forceinline__ float dec_f(unsigned e){
  unsigned b = (e & 0x80000000u) ? (e ^ 0x80000000u) : ~e;
  return __uint_as_float(b);
}

// ---------- LayerNorm (ddof=1, (x-mu)/(sd+eps)*w+b), one wave per row ----------
__global__ void ln_kernel(const float* __restrict__ x, const float* __restrict__ w,
                          const float* __restrict__ b, float* __restrict__ out, int nrows){
  int wid = threadIdx.x >> 6, lane = threadIdx.x & 63;
  int r = blockIdx.x * (blockDim.x >> 6) + wid;
  if (r >= nrows) return;
  float2 v = ((const float2*)(x + (size_t)r*128))[lane];
  float s = v.x + v.y;
  #pragma unroll
  for (int o = 32; o; o >>= 1) s += __shfl_xor(s, o);
  float mu = s * (1.0f/128.0f);
  float d0 = v.x - mu, d1 = v.y - mu;
  float ss = d0*d0 + d1*d1;
  #pragma unroll
  for (int o = 32; o; o >>= 1) ss += __shfl_xor(ss, o);
  float sd = sqrtf(ss * (1.0f/127.0f));
  float inv = 1.0f / (sd + LN_EPS);
  float2 wv = ((const float2*)w)[lane];
  float2 bv = ((const float2*)b)[lane];
  float2 o2 = { d0*inv*wv.x + bv.x, d1*inv*wv.y + bv.y };
  ((float2*)(out + (size_t)r*128))[lane] = o2;
}

// ---------- f32 GEMM: out[M][Nout] = A[M][K] @ W[Nout][K]^T + bias (+relu)(+resid) ----------
template<int RELU, int RESID>
__global__ __launch_bounds__(256) void gemm_kernel(
    const float* __restrict__ A, const float* __restrict__ W,
    const float* __restrict__ bias, const float* __restrict__ resid,
    float* __restrict__ out, int M, int K, int Nout){
  __shared__ __align__(16) float As[32][68];
  __shared__ __align__(16) float Ws[32][68];
  int t = threadIdx.x;
  int tx = t & 15, ty = t >> 4;
  int rb = blockIdx.y * 64, cb = blockIdx.x * 64;
  float acc[4][4] = {};
  for (int kt = 0; kt < K; kt += 32){
    #pragma unroll
    for (int i = 0; i < 8; ++i){
      int p = i*256 + t;
      int kq = p & 31, r = p >> 5;
      int gr = rb + r;
      As[kq][r] = (gr < M) ? A[(size_t)gr*K + kt + kq] : 0.0f;
      Ws[kq][r] = W[(size_t)(cb + r)*K + kt + kq];
    }
    __syncthreads();
    #pragma unroll
    for (int kq = 0; kq < 32; ++kq){
      float4 av = *(const float4*)&As[kq][ty*4];
      float4 wv = *(const float4*)&Ws[kq][tx*4];
      float a_[4] = {av.x, av.y, av.z, av.w};
      float w_[4] = {wv.x, wv.y, wv.z, wv.w};
      #pragma unroll
      for (int i = 0; i < 4; ++i)
        #pragma unroll
        for (int j = 0; j < 4; ++j)
          acc[i][j] = fmaf(a_[i], w_[j], acc[i][j]);
    }
    __syncthreads();
  }
  #pragma unroll
  for (int i = 0; i < 4; ++i){
    int r = rb + ty*4 + i;
    if (r >= M) continue;
    #pragma unroll
    for (int j = 0; j < 4; ++j){
      int c = cb + tx*4 + j;
      float vv = acc[i][j] + bias[c];
      if (RELU) vv = fmaxf(vv, 0.0f);
      if (RESID) vv += resid[(size_t)r*Nout + c];
      out[(size_t)r*Nout + c] = vv;
    }
  }
}

// ---------- edge phase ----------
// scores[e][h] = (q[col[e],h,:] . k[row[e],h,:]) / 4 ; atomic segmented max over row
__global__ void edge_scores_kernel(const float* __restrict__ q, const float* __restrict__ k,
                                   const int* __restrict__ ei, float* __restrict__ score,
                                   unsigned* __restrict__ smax, int E){
  int t = blockIdx.x*blockDim.x + threadIdx.x;
  if (t >= E*H_HEADS) return;
  int e = t >> 3, h = t & 7;
  int row = ei[2*e], col = ei[2*e+1];
  const float4* qp = (const float4*)(q + (size_t)col*128 + h*16);
  const float4* kp = (const float4*)(k + (size_t)row*128 + h*16);
  float s = 0.f;
  #pragma unroll
  for (int i = 0; i < 4; ++i){
    float4 a = qp[i], b = kp[i];
    s += a.x*b.x + a.y*b.y + a.z*b.z + a.w*b.w;
  }
  s *= 0.25f;  // 1/sqrt(16)
  score[t] = s;
  atomicMax(&smax[(size_t)row*8 + h], enc_f(s));
}

// ex = exp(score - smax[row]); atomic segmented sum over row
__global__ void edge_exp_kernel(float* __restrict__ score, const int* __restrict__ ei,
                                const unsigned* __restrict__ smax, float* __restrict__ denom, int E){
  int t = blockIdx.x*blockDim.x + threadIdx.x;
  if (t >= E*H_HEADS) return;
  int e = t >> 3, h = t & 7;
  int row = ei[2*e];
  float m = dec_f(smax[(size_t)row*8 + h]);
  float ex = __expf(score[t] - m);
  score[t] = ex;
  atomicAdd(&denom[(size_t)row*8 + h], ex);
}

// agg[col] += (ex/denom[row]) * v[row]
__global__ void edge_scatter_kernel(const float* __restrict__ v, const float* __restrict__ ex,
                                    const float* __restrict__ denom, const int* __restrict__ ei,
                                    float* __restrict__ agg, int E){
  int t = blockIdx.x*blockDim.x + threadIdx.x;
  if (t >= E*H_HEADS) return;
  int e = t >> 3, h = t & 7;
  int row = ei[2*e], col = ei[2*e+1];
  float alpha = ex[t] / denom[(size_t)row*8 + h];
  const float4* vp = (const float4*)(v + (size_t)row*128 + h*16);
  float* ap = agg + (size_t)col*128 + h*16;
  #pragma unroll
  for (int i = 0; i < 4; ++i){
    float4 vv = vp[i];
    atomicAdd(ap + 4*i + 0, alpha*vv.x);
    atomicAdd(ap + 4*i + 1, alpha*vv.y);
    atomicAdd(ap + 4*i + 2, alpha*vv.z);
    atomicAdd(ap + 4*i + 3, alpha*vv.w);
  }
}

extern "C" void kernel_launch(void* const* d_in, const int* in_sizes, int n_in,
                              void* d_out, int out_size, void* d_ws, size_t ws_size,
                              hipStream_t stream){
  const float* feats = (const float*)d_in[0];
  const int*   ei    = (const int*)  d_in[1];
  const float* Wq = (const float*)d_in[2];
  const float* bq = (const float*)d_in[3];
  const float* Wk = (const float*)d_in[4];
  const float* bk = (const float*)d_in[5];
  const float* Wv = (const float*)d_in[6];
  const float* bv = (const float*)d_in[7];
  const float* Wo = (const float*)d_in[8];
  const float* bo = (const float*)d_in[9];
  const float* ln1w = (const float*)d_in[10];
  const float* ln1b = (const float*)d_in[11];
  const float* ln2w = (const float*)d_in[12];
  const float* ln2b = (const float*)d_in[13];
  const float* W1 = (const float*)d_in[14];
  const float* b1 = (const float*)d_in[15];
  const float* W2 = (const float*)d_in[16];
  const float* b2 = (const float*)d_in[17];
  float* outp = (float*)d_out;

  int n = in_sizes[0] / 128;      // 50000 nodes
  int E = in_sizes[1] / 2;        // 800000 edges

  const size_t ND = (size_t)n * 128;          // 6.4M
  const size_t EH = (size_t)E * H_HEADS;      // 6.4M
  const size_t NH = (size_t)n * H_HEADS;      // 0.4M

  // workspace layout (floats): x2 | q | kbuf | vbuf | ex | agg | smax | denom
  // q..ex block (4*ND floats min) is reused as h1 (n x 512) in the FFN phase.
  float* ws   = (float*)d_ws;
  float* x2   = ws;
  float* q    = x2   + ND;
  float* kbuf = q    + ND;
  float* vbuf = kbuf + ND;
  float* ex   = vbuf + ND;
  float* agg  = ex   + EH;
  unsigned* smax = (unsigned*)(agg + ND);
  float* denom   = (float*)(smax + NH);
  float* h1 = q;

  (void)hipMemsetAsync(smax,  0, NH*sizeof(unsigned), stream);
  (void)hipMemsetAsync(denom, 0, NH*sizeof(float), stream);
  (void)hipMemsetAsync(agg,   0, ND*sizeof(float), stream);

  // LN1
  ln_kernel<<<(n+3)/4, 256, 0, stream>>>(feats, ln1w, ln1b, x2, n);

  // QKV projections
  dim3 g128(128/64, (n+63)/64);
  gemm_kernel<0,0><<<g128, 256, 0, stream>>>(x2, Wq, bq, nullptr, q,    n, 128, 128);
  gemm_kernel<0,0><<<g128, 256, 0, stream>>>(x2, Wk, bk, nullptr, kbuf, n, 128, 128);
  gemm_kernel<0,0><<<g128, 256, 0, stream>>>(x2, Wv, bv, nullptr, vbuf, n, 128, 128);

  // edge attention
  int eb = (int)((EH + 255)/256);
  edge_scores_kernel <<<eb, 256, 0, stream>>>(q, kbuf, ei, ex, smax, E);
  edge_exp_kernel    <<<eb, 256, 0, stream>>>(ex, ei, smax, denom, E);
  edge_scatter_kernel<<<eb, 256, 0, stream>>>(vbuf, ex, denom, ei, agg, E);

  // attention output projection + residual -> d_out
  gemm_kernel<0,1><<<g128, 256, 0, stream>>>(agg, Wo, bo, feats, outp, n, 128, 128);

  // LN2 (reuse x2)
  ln_kernel<<<(n+3)/4, 256, 0, stream>>>(outp, ln2w, ln2b, x2, n);

  // FFN
  dim3 g512(512/64, (n+63)/64);
  gemm_kernel<1,0><<<g512, 256, 0, stream>>>(x2, W1, b1, nullptr, h1, n, 128, 512);
  gemm_kernel<1,1><<<g128, 256, 0, stream>>>(h1, W2, b2, outp, outp, n, 512, 128);
}

// Round 3
// 878.918 us; speedup vs baseline: 7.2123x; 7.2123x over previous
//
#include <hip/hip_runtime.h>
#include <hip/hip_bf16.h>
#include <math.h>

#define H_HEADS 8
constexpr float LN_EPS = 1e-5f;

// ---------- float atomic-max via order-preserving uint encoding ----------
__device__ __forceinline__ unsigned enc_f(float f){
  unsigned u = __float_as_uint(f);
  return (u & 0x80000000u) ? ~u : (u | 0x80000000u);
}
__device__ __forceinline__ float dec_f(unsigned e){
  unsigned b = (e & 0x80000000u) ? (e ^ 0x80000000u) : ~e;
  return __uint_as_float(b);
}

// ---------- LayerNorm (ddof=1, (x-mu)/(sd+eps)*w+b), one wave per row ----------
__global__ void ln_kernel(const float* __restrict__ x, const float* __restrict__ w,
                          const float* __restrict__ b, float* __restrict__ out, int nrows){
  int wid = threadIdx.x >> 6, lane = threadIdx.x & 63;
  int r = blockIdx.x * (blockDim.x >> 6) + wid;
  if (r >= nrows) return;
  float2 v = ((const float2*)(x + (size_t)r*128))[lane];
  float s = v.x + v.y;
  #pragma unroll
  for (int o = 32; o; o >>= 1) s += __shfl_xor(s, o);
  float mu = s * (1.0f/128.0f);
  float d0 = v.x - mu, d1 = v.y - mu;
  float ss = d0*d0 + d1*d1;
  #pragma unroll
  for (int o = 32; o; o >>= 1) ss += __shfl_xor(ss, o);
  float sd = sqrtf(ss * (1.0f/127.0f));
  float inv = 1.0f / (sd + LN_EPS);
  float2 wv = ((const float2*)w)[lane];
  float2 bv = ((const float2*)b)[lane];
  float2 o2 = { d0*inv*wv.x + bv.x, d1*inv*wv.y + bv.y };
  ((float2*)(out + (size_t)r*128))[lane] = o2;
}

// ---------- f32 GEMM: out[M][Nout] = A[M][K] @ W[Nout][K]^T + bias (+relu)(+resid) ----------
template<int RELU, int RESID>
__global__ __launch_bounds__(256) void gemm_kernel(
    const float* __restrict__ A, const float* __restrict__ W,
    const float* __restrict__ bias, const float* __restrict__ resid,
    float* __restrict__ out, int M, int K, int Nout){
  __shared__ __align__(16) float As[32][68];
  __shared__ __align__(16) float Ws[32][68];
  int t = threadIdx.x;
  int tx = t & 15, ty = t >> 4;
  int rb = blockIdx.y * 64, cb = blockIdx.x * 64;
  float acc[4][4] = {};
  for (int kt = 0; kt < K; kt += 32){
    #pragma unroll
    for (int i = 0; i < 8; ++i){
      int p = i*256 + t;
      int kq = p & 31, r = p >> 5;
      int gr = rb + r;
      As[kq][r] = (gr < M) ? A[(size_t)gr*K + kt + kq] : 0.0f;
      Ws[kq][r] = W[(size_t)(cb + r)*K + kt + kq];
    }
    __syncthreads();
    #pragma unroll
    for (int kq = 0; kq < 32; ++kq){
      float4 av = *(const float4*)&As[kq][ty*4];
      float4 wv = *(const float4*)&Ws[kq][tx*4];
      float a_[4] = {av.x, av.y, av.z, av.w};
      float w_[4] = {wv.x, wv.y, wv.z, wv.w};
      #pragma unroll
      for (int i = 0; i < 4; ++i)
        #pragma unroll
        for (int j = 0; j < 4; ++j)
          acc[i][j] = fmaf(a_[i], w_[j], acc[i][j]);
    }
    __syncthreads();
  }
  #pragma unroll
  for (int i = 0; i < 4; ++i){
    int r = rb + ty*4 + i;
    if (r >= M) continue;
    #pragma unroll
    for (int j = 0; j < 4; ++j){
      int c = cb + tx*4 + j;
      float vv = acc[i][j] + bias[c];
      if (RELU) vv = fmaxf(vv, 0.0f);
      if (RESID) vv += resid[(size_t)r*Nout + c];
      out[(size_t)r*Nout + c] = vv;
    }
  }
}

// ---------- edge phase ----------
// scores[e][h] = (q[col[e],h,:] . k[row[e],h,:]) / 4 ; atomic segmented max over row
__global__ void edge_scores_kernel(const float* __restrict__ q, const float* __restrict__ k,
                                   const int* __restrict__ ei, float* __restrict__ score,
                                   unsigned* __restrict__ smax, int E){
  int t = blockIdx.x*blockDim.x + threadIdx.x;
  if (t >= E*H_HEADS) return;
  int e = t >> 3, h = t & 7;
  int row = ei[2*e], col = ei[2*e+1];
  const float4* qp = (const float4*)(q + (size_t)col*128 + h*16);
  const float4* kp = (const float4*)(k + (size_t)row*128 + h*16);
  float s = 0.f;
  #pragma unroll
  for (int i = 0; i < 4; ++i){
    float4 a = qp[i], b = kp[i];
    s += a.x*b.x + a.y*b.y + a.z*b.z + a.w*b.w;
  }
  s *= 0.25f;  // 1/sqrt(16)
  score[t] = s;
  atomicMax(&smax[(size_t)row*8 + h], enc_f(s));
}

// ex = exp(score - smax[row]); atomic segmented sum over row
__global__ void edge_exp_kernel(float* __restrict__ score, const int* __restrict__ ei,
                                const unsigned* __restrict__ smax, float* __restrict__ denom, int E){
  int t = blockIdx.x*blockDim.x + threadIdx.x;
  if (t >= E*H_HEADS) return;
  int e = t >> 3, h = t & 7;
  int row = ei[2*e];
  float m = dec_f(smax[(size_t)row*8 + h]);
  float ex = __expf(score[t] - m);
  score[t] = ex;
  atomicAdd(&denom[(size_t)row*8 + h], ex);
}

// alpha = ex / denom[row]   (in place on ex)
__global__ void alpha_kernel(float* __restrict__ ex, const float* __restrict__ denom,
                             const int* __restrict__ ei, int E){
  int t = blockIdx.x*blockDim.x + threadIdx.x;
  if (t >= E*H_HEADS) return;
  int e = t >> 3, h = t & 7;
  int row = ei[2*e];
  ex[t] = ex[t] / denom[(size_t)row*8 + h];
}

// ---------- CSR build (counting sort by col) ----------
__global__ void hist_kernel(const int* __restrict__ ei, int* __restrict__ cnt, int E){
  int e = blockIdx.x*blockDim.x + threadIdx.x;
  if (e < E) atomicAdd(&cnt[ei[2*e+1]], 1);
}

// single-block exclusive scan over n counters -> ptr[0..n], cursor copy
__global__ __launch_bounds__(1024) void scan_kernel(const int* __restrict__ cnt,
                                                    int* __restrict__ ptr,
                                                    int* __restrict__ cursor, int n){
  __shared__ int sums[1024];
  int t = threadIdx.x;
  int chunk = (n + 1023) / 1024;
  int lo = t*chunk, hi = min(lo+chunk, n);
  int s = 0;
  for (int i = lo; i < hi; ++i) s += cnt[i];
  sums[t] = s;
  __syncthreads();
  #pragma unroll
  for (int off = 1; off < 1024; off <<= 1){
    int v = (t >= off) ? sums[t-off] : 0;
    __syncthreads();
    sums[t] += v;
    __syncthreads();
  }
  int base = (t == 0) ? 0 : sums[t-1];
  for (int i = lo; i < hi; ++i){
    ptr[i] = base;
    cursor[i] = base;
    base += cnt[i];
  }
  if (t == 1023) ptr[n] = base;
}

__global__ void fill_kernel(const int* __restrict__ ei, int* __restrict__ cursor,
                            int* __restrict__ csr_e, int* __restrict__ csr_row, int E){
  int e = blockIdx.x*blockDim.x + threadIdx.x;
  if (e >= E) return;
  int row = ei[2*e], col = ei[2*e+1];
  int pos = atomicAdd(&cursor[col], 1);
  csr_e[pos] = e;
  csr_row[pos] = row;
}

// ---------- gather aggregation: agg[node] = sum_{e in CSR[node]} alpha[e,h]*v[row_e] ----------
__global__ void agg_kernel(const float* __restrict__ v, const float* __restrict__ alpha,
                           const int* __restrict__ ptr, const int* __restrict__ csr_e,
                           const int* __restrict__ csr_row, float* __restrict__ agg, int n){
  int wid = threadIdx.x >> 6, lane = threadIdx.x & 63;
  int node = blockIdx.x * (blockDim.x >> 6) + wid;
  if (node >= n) return;
  int lo = ptr[node], hi = ptr[node+1];
  int h = lane >> 3;              // lane covers dims 2l,2l+1 -> head = (2l)/16 = l/8
  float2 acc = {0.f, 0.f};
  for (int j = lo; j < hi; ++j){
    int e = csr_e[j], row = csr_row[j];
    float a = alpha[(size_t)e*8 + h];
    float2 vv = ((const float2*)(v + (size_t)row*128))[lane];
    acc.x = fmaf(a, vv.x, acc.x);
    acc.y = fmaf(a, vv.y, acc.y);
  }
  ((float2*)(agg + (size_t)node*128))[lane] = acc;
}

extern "C" void kernel_launch(void* const* d_in, const int* in_sizes, int n_in,
                              void* d_out, int out_size, void* d_ws, size_t ws_size,
                              hipStream_t stream){
  const float* feats = (const float*)d_in[0];
  const int*   ei    = (const int*)  d_in[1];
  const float* Wq = (const float*)d_in[2];
  const float* bq = (const float*)d_in[3];
  const float* Wk = (const float*)d_in[4];
  const float* bk = (const float*)d_in[5];
  const float* Wv = (const float*)d_in[6];
  const float* bv = (const float*)d_in[7];
  const float* Wo = (const float*)d_in[8];
  const float* bo = (const float*)d_in[9];
  const float* ln1w = (const float*)d_in[10];
  const float* ln1b = (const float*)d_in[11];
  const float* ln2w = (const float*)d_in[12];
  const float* ln2b = (const float*)d_in[13];
  const float* W1 = (const float*)d_in[14];
  const float* b1 = (const float*)d_in[15];
  const float* W2 = (const float*)d_in[16];
  const float* b2 = (const float*)d_in[17];
  float* outp = (float*)d_out;

  int n = in_sizes[0] / 128;      // 50000 nodes
  int E = in_sizes[1] / 2;        // 800000 edges

  const size_t ND = (size_t)n * 128;          // 6.4M
  const size_t EH = (size_t)E * H_HEADS;      // 6.4M
  const size_t NH = (size_t)n * H_HEADS;      // 0.4M

  // workspace layout (4B elems):
  //   x2 | q | kbuf | vbuf | ex | agg | smax | denom | cnt | ptr | cursor | csr_e | csr_row
  // q..ex block (>= n*512 floats) is reused as h1 in the FFN phase.
  float* ws   = (float*)d_ws;
  float* x2   = ws;
  float* q    = x2   + ND;
  float* kbuf = q    + ND;
  float* vbuf = kbuf + ND;
  float* ex   = vbuf + ND;
  float* agg  = ex   + EH;
  unsigned* smax = (unsigned*)(agg + ND);
  float* denom   = (float*)(smax + NH);
  int* cnt    = (int*)(denom + NH);
  int* ptr    = cnt + n;
  int* cursor = ptr + (n + 1);
  int* csr_e  = cursor + n;
  int* csr_row= csr_e + E;
  float* h1 = q;

  (void)hipMemsetAsync(smax,  0, NH*sizeof(unsigned), stream);
  (void)hipMemsetAsync(denom, 0, NH*sizeof(float), stream);
  (void)hipMemsetAsync(cnt,   0, n*sizeof(int), stream);

  // CSR build (independent of LN/GEMM results — issue early)
  int ebE = (E + 255)/256;
  hist_kernel<<<ebE, 256, 0, stream>>>(ei, cnt, E);
  scan_kernel<<<1, 1024, 0, stream>>>(cnt, ptr, cursor, n);
  fill_kernel<<<ebE, 256, 0, stream>>>(ei, cursor, csr_e, csr_row, E);

  // LN1
  ln_kernel<<<(n+3)/4, 256, 0, stream>>>(feats, ln1w, ln1b, x2, n);

  // QKV projections
  dim3 g128(128/64, (n+63)/64);
  gemm_kernel<0,0><<<g128, 256, 0, stream>>>(x2, Wq, bq, nullptr, q,    n, 128, 128);
  gemm_kernel<0,0><<<g128, 256, 0, stream>>>(x2, Wk, bk, nullptr, kbuf, n, 128, 128);
  gemm_kernel<0,0><<<g128, 256, 0, stream>>>(x2, Wv, bv, nullptr, vbuf, n, 128, 128);

  // edge attention (softmax over row segments)
  int eb = (int)((EH + 255)/256);
  edge_scores_kernel<<<eb, 256, 0, stream>>>(q, kbuf, ei, ex, smax, E);
  edge_exp_kernel   <<<eb, 256, 0, stream>>>(ex, ei, smax, denom, E);
  alpha_kernel      <<<eb, 256, 0, stream>>>(ex, denom, ei, E);

  // gather aggregation over col segments (no atomics)
  agg_kernel<<<(n+3)/4, 256, 0, stream>>>(vbuf, ex, ptr, csr_e, csr_row, agg, n);

  // attention output projection + residual -> d_out
  gemm_kernel<0,1><<<g128, 256, 0, stream>>>(agg, Wo, bo, feats, outp, n, 128, 128);

  // LN2 (reuse x2)
  ln_kernel<<<(n+3)/4, 256, 0, stream>>>(outp, ln2w, ln2b, x2, n);

  // FFN
  dim3 g512(512/64, (n+63)/64);
  gemm_kernel<1,0><<<g512, 256, 0, stream>>>(x2, W1, b1, nullptr, h1, n, 128, 512);
  gemm_kernel<1,1><<<g128, 256, 0, stream>>>(h1, W2, b2, outp, outp, n, 512, 128);
}

// Round 4
// 742.453 us; speedup vs baseline: 8.5379x; 1.1838x over previous
//
#include <hip/hip_runtime.h>
#include <hip/hip_bf16.h>
#include <math.h>

#define H_HEADS 8
constexpr float LN_EPS = 1e-5f;

using short8 = __attribute__((ext_vector_type(8))) short;
using f32x4  = __attribute__((ext_vector_type(4))) float;

__device__ __forceinline__ ushort f2bf(float v){
  __hip_bfloat16 h = __float2bfloat16(v);
  return *reinterpret_cast<ushort*>(&h);
}

// ---------- float atomic-max via order-preserving uint encoding ----------
__device__ __forceinline__ unsigned enc_f(float f){
  unsigned u = __float_as_uint(f);
  return (u & 0x80000000u) ? ~u : (u | 0x80000000u);
}
__device__ __forceinline__ float dec_f(unsigned e){
  unsigned b = (e & 0x80000000u) ? (e ^ 0x80000000u) : ~e;
  return __uint_as_float(b);
}

// ---------- LayerNorm (ddof=1), f32 in -> bf16 out, one wave per row ----------
__global__ void ln_kernel(const float* __restrict__ x, const float* __restrict__ w,
                          const float* __restrict__ b, ushort* __restrict__ out, int nrows){
  int wid = threadIdx.x >> 6, lane = threadIdx.x & 63;
  int r = blockIdx.x * (blockDim.x >> 6) + wid;
  if (r >= nrows) return;
  float2 v = ((const float2*)(x + (size_t)r*128))[lane];
  float s = v.x + v.y;
  #pragma unroll
  for (int o = 32; o; o >>= 1) s += __shfl_xor(s, o);
  float mu = s * (1.0f/128.0f);
  float d0 = v.x - mu, d1 = v.y - mu;
  float ss = d0*d0 + d1*d1;
  #pragma unroll
  for (int o = 32; o; o >>= 1) ss += __shfl_xor(ss, o);
  float sd = sqrtf(ss * (1.0f/127.0f));
  float inv = 1.0f / (sd + LN_EPS);
  float2 wv = ((const float2*)w)[lane];
  float2 bv = ((const float2*)b)[lane];
  ushort2 o2 = { f2bf(d0*inv*wv.x + bv.x), f2bf(d1*inv*wv.y + bv.y) };
  ((ushort2*)(out + (size_t)r*128))[lane] = o2;
}

// ---------- weight f32 -> bf16 conversion (all 6 in one launch) ----------
struct CvtArgs { const float* s[6]; ushort* d[6]; int cnt[6]; };
__global__ void cvt6_kernel(CvtArgs a){
  int w = blockIdx.y;
  int i = blockIdx.x*blockDim.x + threadIdx.x;
  if (i < a.cnt[w]) a.d[w][i] = f2bf(a.s[w][i]);
}

// ---------- bf16 MFMA GEMM: out[M][Nout] = A[M][K] @ W[Nout][K]^T + bias ----------
// one wave = 16 rows x (NT*16) cols; block = 4 waves = 64 rows. No LDS.
// A,W bf16 row-major (K contiguous). 16x16x32 MFMA:
//   A-frag: lane l holds A[l&15][(l>>4)*8 + j], j=0..7  (one 16B load)
//   B-frag: lane l holds W[col=l&15][(l>>4)*8 + j]      (one 16B load)
//   C/D  : col = lane&15, row = (lane>>4)*4 + i  [m89/m91 verified]
template<int NT, int RELU, int RESID, int OUT_BF16>
__global__ __launch_bounds__(256) void mfma_gemm(
    const ushort* __restrict__ A, const ushort* __restrict__ W,
    const float* __restrict__ bias, const float* __restrict__ resid,
    void* __restrict__ out, int M, int K, int Nout){
  int wid = threadIdx.x >> 6, lane = threadIdx.x & 63;
  int mb = blockIdx.x * 64 + wid * 16;
  if (mb >= M) return;
  int cb = blockIdx.y * (NT*16);
  int lrow = lane & 15, kgrp = lane >> 4;
  int row = mb + lrow;
  bool rowok = row < M;
  const ushort* arow = A + (size_t)(rowok ? row : (M-1)) * K + kgrp*8;

  f32x4 acc[NT] = {};
  for (int kt = 0; kt < K; kt += 32){
    short8 af = {};
    if (rowok) af = *(const short8*)(arow + kt);
    #pragma unroll
    for (int nt = 0; nt < NT; ++nt){
      int c = cb + nt*16 + lrow;
      short8 bf = *(const short8*)(W + (size_t)c * K + kt + kgrp*8);
      acc[nt] = __builtin_amdgcn_mfma_f32_16x16x32_bf16(af, bf, acc[nt], 0, 0, 0);
    }
  }

  int r0 = mb + kgrp*4;
  #pragma unroll
  for (int nt = 0; nt < NT; ++nt){
    int c = cb + nt*16 + lrow;
    float bsum = bias[c];
    #pragma unroll
    for (int i = 0; i < 4; ++i){
      int r = r0 + i;
      if (r >= M) continue;
      float v = acc[nt][i] + bsum;
      if (RELU)  v = fmaxf(v, 0.0f);
      if (RESID) v += resid[(size_t)r*Nout + c];
      if (OUT_BF16) ((ushort*)out)[(size_t)r*Nout + c] = f2bf(v);
      else          ((float*)out)[(size_t)r*Nout + c] = v;
    }
  }
}

// ---------- edge phase (f32 q,k,v) ----------
__global__ void edge_scores_kernel(const float* __restrict__ q, const float* __restrict__ k,
                                   const int* __restrict__ ei, float* __restrict__ score,
                                   unsigned* __restrict__ smax, int E){
  int t = blockIdx.x*blockDim.x + threadIdx.x;
  if (t >= E*H_HEADS) return;
  int e = t >> 3, h = t & 7;
  int row = ei[2*e], col = ei[2*e+1];
  const float4* qp = (const float4*)(q + (size_t)col*128 + h*16);
  const float4* kp = (const float4*)(k + (size_t)row*128 + h*16);
  float s = 0.f;
  #pragma unroll
  for (int i = 0; i < 4; ++i){
    float4 a = qp[i], b = kp[i];
    s += a.x*b.x + a.y*b.y + a.z*b.z + a.w*b.w;
  }
  s *= 0.25f;  // 1/sqrt(16)
  score[t] = s;
  atomicMax(&smax[(size_t)row*8 + h], enc_f(s));
}

__global__ void edge_exp_kernel(float* __restrict__ score, const int* __restrict__ ei,
                                const unsigned* __restrict__ smax, float* __restrict__ denom, int E){
  int t = blockIdx.x*blockDim.x + threadIdx.x;
  if (t >= E*H_HEADS) return;
  int e = t >> 3, h = t & 7;
  int row = ei[2*e];
  float m = dec_f(smax[(size_t)row*8 + h]);
  float ex = __expf(score[t] - m);
  score[t] = ex;
  atomicAdd(&denom[(size_t)row*8 + h], ex);
}

__global__ void alpha_kernel(float* __restrict__ ex, const float* __restrict__ denom,
                             const int* __restrict__ ei, int E){
  int t = blockIdx.x*blockDim.x + threadIdx.x;
  if (t >= E*H_HEADS) return;
  int e = t >> 3, h = t & 7;
  int row = ei[2*e];
  ex[t] = ex[t] / denom[(size_t)row*8 + h];
}

// ---------- CSR build (counting sort by col) ----------
__global__ void hist_kernel(const int* __restrict__ ei, int* __restrict__ cnt, int E){
  int e = blockIdx.x*blockDim.x + threadIdx.x;
  if (e < E) atomicAdd(&cnt[ei[2*e+1]], 1);
}

__global__ __launch_bounds__(1024) void scan_kernel(const int* __restrict__ cnt,
                                                    int* __restrict__ ptr,
                                                    int* __restrict__ cursor, int n){
  __shared__ int sums[1024];
  int t = threadIdx.x;
  int chunk = (n + 1023) / 1024;
  int lo = t*chunk, hi = min(lo+chunk, n);
  int s = 0;
  for (int i = lo; i < hi; ++i) s += cnt[i];
  sums[t] = s;
  __syncthreads();
  #pragma unroll
  for (int off = 1; off < 1024; off <<= 1){
    int v = (t >= off) ? sums[t-off] : 0;
    __syncthreads();
    sums[t] += v;
    __syncthreads();
  }
  int base = (t == 0) ? 0 : sums[t-1];
  for (int i = lo; i < hi; ++i){
    ptr[i] = base;
    cursor[i] = base;
    base += cnt[i];
  }
  if (t == 1023) ptr[n] = base;
}

__global__ void fill_kernel(const int* __restrict__ ei, int* __restrict__ cursor,
                            int* __restrict__ csr_e, int* __restrict__ csr_row, int E){
  int e = blockIdx.x*blockDim.x + threadIdx.x;
  if (e >= E) return;
  int row = ei[2*e], col = ei[2*e+1];
  int pos = atomicAdd(&cursor[col], 1);
  csr_e[pos] = e;
  csr_row[pos] = row;
}

// ---------- gather aggregation -> bf16 agg ----------
__global__ void agg_kernel(const float* __restrict__ v, const float* __restrict__ alpha,
                           const int* __restrict__ ptr, const int* __restrict__ csr_e,
                           const int* __restrict__ csr_row, ushort* __restrict__ agg, int n){
  int wid = threadIdx.x >> 6, lane = threadIdx.x & 63;
  int node = blockIdx.x * (blockDim.x >> 6) + wid;
  if (node >= n) return;
  int lo = ptr[node], hi = ptr[node+1];
  int h = lane >> 3;
  float2 acc = {0.f, 0.f};
  for (int j = lo; j < hi; ++j){
    int e = csr_e[j], row = csr_row[j];
    float a = alpha[(size_t)e*8 + h];
    float2 vv = ((const float2*)(v + (size_t)row*128))[lane];
    acc.x = fmaf(a, vv.x, acc.x);
    acc.y = fmaf(a, vv.y, acc.y);
  }
  ushort2 o2 = { f2bf(acc.x), f2bf(acc.y) };
  ((ushort2*)(agg + (size_t)node*128))[lane] = o2;
}

extern "C" void kernel_launch(void* const* d_in, const int* in_sizes, int n_in,
                              void* d_out, int out_size, void* d_ws, size_t ws_size,
                              hipStream_t stream){
  const float* feats = (const float*)d_in[0];
  const int*   ei    = (const int*)  d_in[1];
  const float* Wq = (const float*)d_in[2];
  const float* bq = (const float*)d_in[3];
  const float* Wk = (const float*)d_in[4];
  const float* bk = (const float*)d_in[5];
  const float* Wv = (const float*)d_in[6];
  const float* bv = (const float*)d_in[7];
  const float* Wo = (const float*)d_in[8];
  const float* bo = (const float*)d_in[9];
  const float* ln1w = (const float*)d_in[10];
  const float* ln1b = (const float*)d_in[11];
  const float* ln2w = (const float*)d_in[12];
  const float* ln2b = (const float*)d_in[13];
  const float* W1 = (const float*)d_in[14];
  const float* b1 = (const float*)d_in[15];
  const float* W2 = (const float*)d_in[16];
  const float* b2 = (const float*)d_in[17];
  float* outp = (float*)d_out;

  int n = in_sizes[0] / 128;      // 50000 nodes
  int E = in_sizes[1] / 2;        // 800000 edges

  const size_t ND = (size_t)n * 128;          // 6.4M
  const size_t EH = (size_t)E * H_HEADS;      // 6.4M
  const size_t NH = (size_t)n * H_HEADS;      // 0.4M

  // workspace (4B units):
  //  x2b(ND/2) | q(ND) | k(ND) | v(ND) | ex(EH) | aggb(ND/2) | smax(NH) | denom(NH)
  //  | cnt(n) | ptr(n+4 pad) | cursor(n) | csr_e(E) | csr_row(E) | wbuf(bf16 weights)
  float* ws = (float*)d_ws;
  ushort* x2b  = (ushort*)ws;                 // ND bf16
  float* q     = ws + ND/2;
  float* kbuf  = q + ND;
  float* vbuf  = kbuf + ND;
  float* ex    = vbuf + ND;
  ushort* aggb = (ushort*)(ex + EH);          // ND bf16
  unsigned* smax = (unsigned*)(aggb + ND);    // ND ushorts = ND/2 units
  float* denom   = (float*)(smax + NH);
  int* cnt    = (int*)(denom + NH);
  int* ptr    = cnt + n;
  int* cursor = ptr + (n + 4);                // +4 pad keeps wbuf 16B-aligned
  int* csr_e  = cursor + n;
  int* csr_row= csr_e + E;
  ushort* wbuf = (ushort*)(csr_row + E);
  ushort* Wqb = wbuf;
  ushort* Wkb = Wqb + 16384;
  ushort* Wvb = Wkb + 16384;
  ushort* Wob = Wvb + 16384;
  ushort* W1b = Wob + 16384;
  ushort* W2b = W1b + 65536;
  ushort* h1  = (ushort*)q;                   // n*512 bf16, aliases q..k

  (void)hipMemsetAsync(smax,  0, NH*sizeof(unsigned), stream);
  (void)hipMemsetAsync(denom, 0, NH*sizeof(float), stream);
  (void)hipMemsetAsync(cnt,   0, n*sizeof(int), stream);

  // weight conversion + CSR build (independent of LN/GEMM results)
  CvtArgs ca;
  ca.s[0]=Wq; ca.s[1]=Wk; ca.s[2]=Wv; ca.s[3]=Wo; ca.s[4]=W1; ca.s[5]=W2;
  ca.d[0]=Wqb; ca.d[1]=Wkb; ca.d[2]=Wvb; ca.d[3]=Wob; ca.d[4]=W1b; ca.d[5]=W2b;
  ca.cnt[0]=ca.cnt[1]=ca.cnt[2]=ca.cnt[3]=16384; ca.cnt[4]=ca.cnt[5]=65536;
  cvt6_kernel<<<dim3(65536/256, 6), 256, 0, stream>>>(ca);

  int ebE = (E + 255)/256;
  hist_kernel<<<ebE, 256, 0, stream>>>(ei, cnt, E);
  scan_kernel<<<1, 1024, 0, stream>>>(cnt, ptr, cursor, n);
  fill_kernel<<<ebE, 256, 0, stream>>>(ei, cursor, csr_e, csr_row, E);

  // LN1 -> bf16
  ln_kernel<<<(n+3)/4, 256, 0, stream>>>(feats, ln1w, ln1b, x2b, n);

  // QKV projections (bf16 MFMA, f32 out)
  int gm = (n + 63)/64;
  mfma_gemm<8,0,0,0><<<dim3(gm,1), 256, 0, stream>>>(x2b, Wqb, bq, nullptr, q,    n, 128, 128);
  mfma_gemm<8,0,0,0><<<dim3(gm,1), 256, 0, stream>>>(x2b, Wkb, bk, nullptr, kbuf, n, 128, 128);
  mfma_gemm<8,0,0,0><<<dim3(gm,1), 256, 0, stream>>>(x2b, Wvb, bv, nullptr, vbuf, n, 128, 128);

  // edge attention (softmax over row segments)
  int eb = (int)((EH + 255)/256);
  edge_scores_kernel<<<eb, 256, 0, stream>>>(q, kbuf, ei, ex, smax, E);
  edge_exp_kernel   <<<eb, 256, 0, stream>>>(ex, ei, smax, denom, E);
  alpha_kernel      <<<eb, 256, 0, stream>>>(ex, denom, ei, E);

  // gather aggregation (no atomics) -> bf16
  agg_kernel<<<(n+3)/4, 256, 0, stream>>>(vbuf, ex, ptr, csr_e, csr_row, aggb, n);

  // attention out projection + residual -> d_out (f32)
  mfma_gemm<8,0,1,0><<<dim3(gm,1), 256, 0, stream>>>(aggb, Wob, bo, feats, outp, n, 128, 128);

  // LN2 -> bf16
  ln_kernel<<<(n+3)/4, 256, 0, stream>>>(outp, ln2w, ln2b, x2b, n);

  // FFN: h1 = relu(x2 @ W1^T + b1) in bf16; out += relu(h1 @ W2^T + b2)
  mfma_gemm<8,1,0,1><<<dim3(gm,4), 256, 0, stream>>>(x2b, W1b, b1, nullptr, h1,  n, 128, 512);
  mfma_gemm<8,1,1,0><<<dim3(gm,1), 256, 0, stream>>>(h1,  W2b, b2, outp,    outp, n, 512, 128);
}